// Round 1
// 3812.006 us; speedup vs baseline: 1.1791x; 1.1791x over previous
//
#include <hip/hip_runtime.h>

typedef __bf16 bf16x8 __attribute__((ext_vector_type(8)));
typedef float f32x4 __attribute__((ext_vector_type(4)));
typedef unsigned u32x4 __attribute__((ext_vector_type(4)));
typedef unsigned short u16;

constexpr int T = 256, B = 64, D = 512, H = 1024;
constexpr int G4 = 4 * H;
constexpr int NBLK = 128;   // 64 blocks layer0 + 64 blocks layer1 (1 block/CU)
constexpr int NTHR = 256;   // 4 waves; wave = one K-quarter, all 4 gates

// ---- workspace layout (bytes) ----
constexpr size_t OFF_WX0 = 0;                                   // Wih0 bf16 [4096][512]
constexpr size_t OFF_WH0 = OFF_WX0 + (size_t)G4 * D * 2;        // Whh0 bf16 [4096][1024]
constexpr size_t OFF_WX1 = OFF_WH0 + (size_t)G4 * H * 2;        // Wih1 bf16 [4096][1024]
constexpr size_t OFF_WH1 = OFF_WX1 + (size_t)G4 * H * 2;        // Whh1 bf16 [4096][1024]
constexpr size_t OFF_XIN = OFF_WH1 + (size_t)G4 * H * 2;        // input bf16 [T][B][D]
constexpr size_t OFF_XS1 = OFF_XIN + (size_t)T * B * D * 2;     // h0-out ring bf16 [4][B][H]
constexpr size_t OFF_H1B = OFF_XS1 + (size_t)4 * B * H * 2;     // h1 state bf16 [2][B][H]
constexpr size_t OFF_B0  = OFF_H1B + (size_t)2 * B * H * 2;     // bias0 f32 [4096]
constexpr size_t OFF_B1  = OFF_B0 + (size_t)G4 * 4;             // bias1 f32 [4096]
constexpr size_t OFF_FLG = OFF_B1 + (size_t)G4 * 4;             // 128 u32 per-block step flags

__device__ __forceinline__ u16 f2bf(float f) {
  unsigned u = __builtin_bit_cast(unsigned, f);
  u += 0x7fffu + ((u >> 16) & 1u);
  return (u16)(u >> 16);
}

__device__ __forceinline__ f32x4 mfma16(bf16x8 a, bf16x8 b, f32x4 c) {
  return __builtin_amdgcn_mfma_f32_16x16x32_bf16(a, b, c, 0, 0, 0);
}

__device__ __forceinline__ float sigm(float x) { return 1.f / (1.f + expf(-x)); }

// ---------------- prep kernels ----------------
__global__ void cvt_bf16(const float* __restrict__ src, u16* __restrict__ dst, int n4) {
  int i = blockIdx.x * blockDim.x + threadIdx.x;
  int st = gridDim.x * blockDim.x;
  for (; i < n4; i += st) {
    float4 v = reinterpret_cast<const float4*>(src)[i];
    ushort4 o;
    o.x = f2bf(v.x); o.y = f2bf(v.y); o.z = f2bf(v.z); o.w = f2bf(v.w);
    reinterpret_cast<ushort4*>(dst)[i] = o;
  }
}

__global__ void init_state(const float* __restrict__ h0,
                           u16* __restrict__ xs1, u16* __restrict__ h1buf,
                           const float* __restrict__ bih0, const float* __restrict__ bhh0,
                           const float* __restrict__ bih1, const float* __restrict__ bhh1,
                           float* __restrict__ bias0, float* __restrict__ bias1,
                           unsigned* __restrict__ flags) {
  int i = blockIdx.x * blockDim.x + threadIdx.x;
  if (i < NBLK) flags[i] = 0u;             // per-block step flags (replay-safe reset)
  if (i < 2 * B * H) {
    int l = i / (B * H), rem = i % (B * H);
    int b = rem / H, k = rem % H;
    u16 v = f2bf(h0[(size_t)b * 2 * H + (size_t)l * H + k]);
    if (l == 0) xs1[(size_t)b * H + k] = v;   // ring slot 0 = initial h for layer0
    else        h1buf[(size_t)b * H + k] = v; // parity 0 = initial h for layer1
  }
  if (i < G4) {
    bias0[i] = bih0[i] + bhh0[i];
    bias1[i] = bih1[i] + bhh1[i];
  }
}

// ---------------- persistent pipelined LSTM ----------------
// Per block: 16 h-columns, all 4 gates, all 64 batches.
// Wave ks (0..3) owns K-quarter; weights register-resident.
// Cross-block protocol (per step):
//   h stores  : agent-scope write-through u32 atomics  -> at LLC once vmcnt==0
//   barrier   : per-block flag store + distributed poll (no RMW, no line contention)
//   acquire   : single buffer_inv per CU (tid0 fence) so PLAIN h loads (L2-shared
//               within an XCD) never see stale lines. No buffer_wbl2 anywhere.
template <int L>
__device__ __forceinline__ void run_layer(
    const u16* __restrict__ xin, const u16* __restrict__ wx, const u16* __restrict__ wh,
    const float* __restrict__ bias, u16* __restrict__ xs1, u16* __restrict__ h1b,
    const float* __restrict__ c0, const int* __restrict__ reset,
    float* __restrict__ out, unsigned* __restrict__ flags, int col0,
    f32x4* __restrict__ red, unsigned* __restrict__ rbits, float* __restrict__ lbias) {
  constexpr int KX  = L ? H : D;      // x-part K
  constexpr int NCX = KX / 32;        // x chunks (16 or 32)
  constexpr int NC  = NCX + H / 32;   // total K chunks (48 or 64)
  constexpr int NCW = NC / 4;         // chunks per wave (12 or 16)
  const size_t BH = (size_t)B * H;
  const size_t OUT_HN = (size_t)T * BH;
  const size_t OUT_CN = OUT_HN + 2 * BH;

  const int tid  = threadIdx.x;
  const int ks   = tid >> 6;          // wave = K-quarter
  const int lane = tid & 63;
  const int q    = lane >> 4;
  const int ln   = lane & 15;
  const int c0i  = ks * NCW;

  // ---- one-time LDS prep: packed reset bits + this block's bias rows
  for (int w = tid; w < 2 * T; w += NTHR) {
    const int t = w >> 1, half = (w & 1) * 32;
    unsigned v = 0;
#pragma unroll 8
    for (int i = 0; i < 32; ++i) v |= (unsigned)(reset[t * B + half + i] & 1) << i;
    rbits[w] = v;
  }
  if (tid < 64) lbias[tid] = bias[(tid >> 4) * H + col0 + (tid & 15)];

  // ---- preload this wave's weight fragments, PIN in regs
  u32x4 wreg[4][NCW];
#pragma unroll
  for (int g = 0; g < 4; ++g)
#pragma unroll
    for (int cc = 0; cc < NCW; ++cc) {
      const int c = c0i + cc;
      const u16* W = (c < NCX) ? wx : wh;
      const int stride = (c < NCX) ? KX : H;
      const int kk = ((c < NCX) ? c : c - NCX) * 32 + q * 8;
      wreg[g][cc] = *reinterpret_cast<const u32x4*>(
          W + (size_t)(g * H + col0 + ln) * stride + kk);
    }
#pragma unroll
  for (int g = 0; g < 4; ++g)
#pragma unroll
    for (int cc = 0; cc < NCW; ++cc)
      asm volatile("" : "+v"(wreg[g][cc]));   // opaque: no remat, must stay in regs

  // ---- cell-update state: thread owns one acc-quad = batches b0..b0+3, col cl
  const int b0 = (tid >> 4) * 4;
  const int cl = col0 + (tid & 15);
  float creg[4];
#pragma unroll
  for (int r = 0; r < 4; ++r)
    creg[r] = c0[(size_t)(b0 + r) * 2 * H + (size_t)L * H + cl];

  __syncthreads();
  float bval[4];
#pragma unroll
  for (int g = 0; g < 4; ++g) bval[g] = lbias[g * 16 + (tid & 15)];

  for (int s = 0; s <= T; ++s) {
    const bool active = (L == 0) ? (s < T) : (s >= 1);
    if (active) {
      const int t = (L == 0) ? s : s - 1;

      f32x4 acc[4][4];
#pragma unroll
      for (int g = 0; g < 4; ++g)
#pragma unroll
        for (int m = 0; m < 4; ++m) acc[g][m] = (f32x4){0.f, 0.f, 0.f, 0.f};

      const unsigned rw0 = rbits[2 * t], rw1 = rbits[2 * t + 1];
      const int rz[4] = {(int)((rw0 >> ln) & 1u), (int)((rw0 >> (16 + ln)) & 1u),
                         (int)((rw1 >> ln) & 1u), (int)((rw1 >> (16 + ln)) & 1u)};

      const u16* xsrc;
      if constexpr (L == 0) xsrc = xin + (size_t)t * B * D;
      else                  xsrc = xs1 + (size_t)((t + 1) & 3) * BH;
      const u16* hsrc = (L == 0) ? xs1 + (size_t)(t & 3) * BH
                                 : h1b + (size_t)(t & 1) * BH;

#pragma unroll
      for (int cc = 0; cc < NCW; ++cc) {
        const int c = c0i + cc;
        uint4 f[4];
        if (c < NCX) {                      // x part (no reset gating)
          const int kk = c * 32 + q * 8;
#pragma unroll
          for (int m = 0; m < 4; ++m)
            f[m] = *reinterpret_cast<const uint4*>(xsrc + (size_t)(16 * m + ln) * KX + kk);
        } else {                            // h part (reset zeroes state)
          const int kk = (c - NCX) * 32 + q * 8;
#pragma unroll
          for (int m = 0; m < 4; ++m) {
            uint4 v = *reinterpret_cast<const uint4*>(hsrc + (size_t)(16 * m + ln) * H + kk);
            f[m] = rz[m] ? make_uint4(0u, 0u, 0u, 0u) : v;
          }
        }
#pragma unroll
        for (int g = 0; g < 4; ++g)
#pragma unroll
          for (int m = 0; m < 4; ++m)
            acc[g][m] = mfma16(__builtin_bit_cast(bf16x8, f[m]),
                               __builtin_bit_cast(bf16x8, wreg[g][cc]), acc[g][m]);
      }

      // ---- dump partials: lane-consecutive f32x4 -> conflict-free ds_write_b128
#pragma unroll
      for (int g = 0; g < 4; ++g)
#pragma unroll
        for (int m = 0; m < 4; ++m)
          red[(g * 4 + ks) * 256 + m * 64 + q * 16 + ln] = acc[g][m];
      __syncthreads();

      // ---- reduce + cell update: thread tid owns cells (b0..b0+3, col cl)
      {
        f32x4 gate[4];
#pragma unroll
        for (int g = 0; g < 4; ++g) {
          f32x4 sum = red[(g * 4 + 0) * 256 + tid];
#pragma unroll
          for (int w = 1; w < 4; ++w) sum += red[(g * 4 + w) * 256 + tid];
          gate[g] = sum + (f32x4){bval[g], bval[g], bval[g], bval[g]};
        }
        const unsigned rstw = rbits[2 * t + (b0 >> 5)] >> (b0 & 31);
        float hv[4];
        u16 hb[4];
#pragma unroll
        for (int r = 0; r < 4; ++r) {
          float cp = ((rstw >> r) & 1u) ? 0.f : creg[r];
          float i_ = sigm(gate[0][r]);
          float f_ = sigm(gate[1][r]);
          float g_ = tanhf(gate[2][r]);
          float o_ = sigm(gate[3][r]);
          float cn = fmaf(f_, cp, i_ * g_);
          float hn = o_ * tanhf(cn);
          creg[r] = cn;
          hv[r] = hn;
          hb[r] = f2bf(hn);
        }
        u16* hdst = (L == 0)
            ? xs1 + (size_t)((t + 1) & 3) * BH
            : h1b + (size_t)((t + 1) & 1) * BH;
        // publish h: agent-scope WRITE-THROUGH u32 stores (at LLC once vmcnt==0;
        // makes the per-step buffer_wbl2 unnecessary). Pack column pairs via
        // lane^1 shuffle; even lanes store rows 0-1, odd lanes rows 2-3.
#pragma unroll
        for (int r = 0; r < 4; ++r) {
          unsigned own = hb[r];
          unsigned oth = (unsigned)__shfl_xor((int)own, 1);
          unsigned pk = (tid & 1) ? ((oth & 0xffffu) | (own << 16))
                                  : (own | (oth << 16));
          if ((r >> 1) == (tid & 1))
            __hip_atomic_store(
                reinterpret_cast<unsigned*>(hdst + (size_t)(b0 + r) * H + (cl & ~1)),
                pk, __ATOMIC_RELAXED, __HIP_MEMORY_SCOPE_AGENT);
        }
        if constexpr (L == 1) {
#pragma unroll
          for (int r = 0; r < 4; ++r)
            __builtin_nontemporal_store(hv[r], &out[(size_t)t * BH + (size_t)(b0 + r) * H + cl]);
        }
        if (t == T - 1) {
#pragma unroll
          for (int r = 0; r < 4; ++r) {
            __builtin_nontemporal_store(
                hv[r], &out[OUT_HN + (size_t)(b0 + r) * 2 * H + (size_t)L * H + cl]);
            __builtin_nontemporal_store(
                creg[r], &out[OUT_CN + (size_t)(b0 + r) * 2 * H + (size_t)L * H + cl]);
          }
        }
      }
    }

    // ---- grid barrier, contention-free:
    //   sync#1 : s_waitcnt vmcnt(0) in every wave -> our agent h-stores are at LLC
    //   flag   : one relaxed agent STORE per block (8 distinct lines, no RMW)
    //   poll   : threads 0..127 each watch one block's flag (coalesced 256B wave
    //            loads; lanes self-retire via exec mask as flags arrive)
    //   acquire: single buffer_inv per CU; its completion is drained by the
    //            vmcnt(0) the compiler emits before sync#2's s_barrier, so all
    //            4 waves' subsequent PLAIN loads see fresh LLC data.
    if (s < T) {
      __syncthreads();
      if (tid == 0)
        __hip_atomic_store(&flags[blockIdx.x], (unsigned)(s + 1),
                           __ATOMIC_RELAXED, __HIP_MEMORY_SCOPE_AGENT);
      if (tid < NBLK) {
        while (__hip_atomic_load(&flags[tid], __ATOMIC_RELAXED,
                                 __HIP_MEMORY_SCOPE_AGENT) <= (unsigned)s)
          __builtin_amdgcn_s_sleep(1);
      }
      if (tid == 0)
        __builtin_amdgcn_fence(__ATOMIC_ACQUIRE, "agent");   // buffer_inv: L1+L2 refresh
      __syncthreads();
    }
  }
}

__global__ void __launch_bounds__(NTHR, 1) lstm_seq(
    const u16* __restrict__ xin,
    const u16* __restrict__ wx0, const u16* __restrict__ wh0,
    const u16* __restrict__ wx1, const u16* __restrict__ wh1,
    const float* __restrict__ bias0, const float* __restrict__ bias1,
    u16* __restrict__ xs1, u16* __restrict__ h1b,
    const float* __restrict__ c0, const int* __restrict__ reset,
    float* __restrict__ out, unsigned* __restrict__ flags) {
  __shared__ f32x4 red[4 * 4 * 256];      // 64 KB partials
  __shared__ unsigned rbits[2 * T];       // 2 KB packed reset bits
  __shared__ float lbias[64];             // this block's 64 bias rows
  const int group = blockIdx.x >> 6;
  const int col0 = (blockIdx.x & 63) << 4;
  if (group == 0)
    run_layer<0>(xin, wx0, wh0, bias0, xs1, h1b, c0, reset, out, flags, col0, red, rbits, lbias);
  else
    run_layer<1>(nullptr, wx1, wh1, bias1, xs1, h1b, c0, reset, out, flags, col0, red, rbits, lbias);
}

extern "C" void kernel_launch(void* const* d_in, const int* in_sizes, int n_in,
                              void* d_out, int out_size, void* d_ws, size_t ws_size,
                              hipStream_t stream) {
  (void)in_sizes; (void)n_in; (void)out_size; (void)ws_size;
  const float* input = (const float*)d_in[0];
  const int*   reset = (const int*)d_in[1];
  const float* h0    = (const float*)d_in[2];
  const float* c0    = (const float*)d_in[3];
  const float* Wih0  = (const float*)d_in[4];
  const float* Whh0  = (const float*)d_in[5];
  const float* bih0  = (const float*)d_in[6];
  const float* bhh0  = (const float*)d_in[7];
  const float* Wih1  = (const float*)d_in[8];
  const float* Whh1  = (const float*)d_in[9];
  const float* bih1  = (const float*)d_in[10];
  const float* bhh1  = (const float*)d_in[11];
  float* out = (float*)d_out;
  char* ws = (char*)d_ws;

  u16* wx0 = (u16*)(ws + OFF_WX0);
  u16* wh0 = (u16*)(ws + OFF_WH0);
  u16* wx1 = (u16*)(ws + OFF_WX1);
  u16* wh1 = (u16*)(ws + OFF_WH1);
  u16* xin = (u16*)(ws + OFF_XIN);
  u16* xs1 = (u16*)(ws + OFF_XS1);
  u16* h1b = (u16*)(ws + OFF_H1B);
  float* pb0 = (float*)(ws + OFF_B0);
  float* pb1 = (float*)(ws + OFF_B1);
  unsigned* flg = (unsigned*)(ws + OFF_FLG);

  cvt_bf16<<<1024, 256, 0, stream>>>(Wih0, wx0, G4 * D / 4);
  cvt_bf16<<<1024, 256, 0, stream>>>(Whh0, wh0, G4 * H / 4);
  cvt_bf16<<<1024, 256, 0, stream>>>(Wih1, wx1, G4 * H / 4);
  cvt_bf16<<<1024, 256, 0, stream>>>(Whh1, wh1, G4 * H / 4);
  cvt_bf16<<<2048, 256, 0, stream>>>(input, xin, T * B * D / 4);
  init_state<<<512, 256, 0, stream>>>(h0, xs1, h1b, bih0, bhh0, bih1, bhh1, pb0, pb1, flg);
  lstm_seq<<<NBLK, NTHR, 0, stream>>>(xin, wx0, wh0, wx1, wh1, pb0, pb1,
                                      xs1, h1b, c0, reset, out, flg);
}

// Round 2
// 3529.077 us; speedup vs baseline: 1.2736x; 1.0802x over previous
//
#include <hip/hip_runtime.h>

typedef __bf16 bf16x8 __attribute__((ext_vector_type(8)));
typedef float f32x4 __attribute__((ext_vector_type(4)));
typedef unsigned u32x4 __attribute__((ext_vector_type(4)));
typedef unsigned short u16;

constexpr int T = 256, B = 64, D = 512, H = 1024;
constexpr int G4 = 4 * H;
constexpr int NBLK = 128;   // 64 blocks layer0 + 64 blocks layer1 (1 block/CU)
constexpr int NTHR = 256;   // 4 waves; wave = one K-quarter, all 4 gates

__device__ __forceinline__ u16 f2bf(float f) {
  unsigned u = __builtin_bit_cast(unsigned, f);
  u += 0x7fffu + ((u >> 16) & 1u);
  return (u16)(u >> 16);
}

__device__ __forceinline__ f32x4 mfma16(bf16x8 a, bf16x8 b, f32x4 c) {
  return __builtin_amdgcn_mfma_f32_16x16x32_bf16(a, b, c, 0, 0, 0);
}

__device__ __forceinline__ float sigm(float x) { return 1.f / (1.f + expf(-x)); }

// ---------------- prep kernels ----------------
__global__ void cvt_bf16(const float* __restrict__ src, u16* __restrict__ dst, int n4) {
  int i = blockIdx.x * blockDim.x + threadIdx.x;
  int st = gridDim.x * blockDim.x;
  for (; i < n4; i += st) {
    float4 v = reinterpret_cast<const float4*>(src)[i];
    ushort4 o;
    o.x = f2bf(v.x); o.y = f2bf(v.y); o.z = f2bf(v.z); o.w = f2bf(v.w);
    reinterpret_cast<ushort4*>(dst)[i] = o;
  }
}

__global__ void init_state(const float* __restrict__ h0,
                           u16* __restrict__ xs1, u16* __restrict__ h1buf,
                           const float* __restrict__ bih0, const float* __restrict__ bhh0,
                           const float* __restrict__ bih1, const float* __restrict__ bhh1,
                           float* __restrict__ bias0, float* __restrict__ bias1,
                           int* __restrict__ flags) {
  int i = blockIdx.x * blockDim.x + threadIdx.x;
  if (i < NBLK) flags[i] = 0;              // per-block step flags (replay-safe reset)
  if (i < 2 * B * H) {
    int l = i / (B * H), rem = i % (B * H);
    int b = rem / H, k = rem % H;
    u16 v = f2bf(h0[(size_t)b * 2 * H + (size_t)l * H + k]);
    if (l == 0) xs1[(size_t)b * H + k] = v;   // slot 0 = initial h for layer0
    else        h1buf[(size_t)b * H + k] = v; // slot 0 = initial h for layer1
  }
  if (i < G4) {
    bias0[i] = bih0[i] + bhh0[i];
    bias1[i] = bih1[i] + bhh1[i];
  }
}

// ---------------- persistent pipelined LSTM ----------------
// Per block: 16 h-columns, all 4 gates, all 64 batches.
// Wave ks (0..3) owns K-quarter; weights register-resident.
//
// Coherence (full mode, s1mask/h1mask = 511): h history is MONOTONIC — each
// step writes a virgin [B][H] region (write-through agent u32 stores -> LLC).
// A line fetched only after its producer's flag is set can never be stale in
// any L1/L2, so fragment loads are PLAIN (compiler-pipelined, L2-shared per
// XCD) and there is NO fence/buffer_inv in the loop. Layer0 never overwrites
// anything layer1 reads -> L0 waits only on its own group and runs ahead.
//
// Fallback (small ws, masks 3/1): round-1 scheme — ring buffers + per-step
// acquire fence (buffer_inv) + full-grid barrier.
template <int L>
__device__ __forceinline__ void run_layer(
    const u16* __restrict__ xin, const u16* __restrict__ wx, const u16* __restrict__ wh,
    const float* __restrict__ bias, u16* __restrict__ xs1, u16* __restrict__ h1b,
    const float* __restrict__ c0, const int* __restrict__ reset,
    float* __restrict__ out, int* __restrict__ flags, int col0,
    f32x4* __restrict__ red, unsigned* __restrict__ rbits, float* __restrict__ lbias,
    const int s1mask, const int h1mask, const int full) {
  constexpr int KX  = L ? H : D;      // x-part K
  constexpr int NCX = KX / 32;        // x chunks (16 or 32)
  constexpr int NC  = NCX + H / 32;   // total K chunks (48 or 64)
  constexpr int NCW = NC / 4;         // chunks per wave (12 or 16)
  const size_t BH = (size_t)B * H;
  const size_t OUT_HN = (size_t)T * BH;
  const size_t OUT_CN = OUT_HN + 2 * BH;

  const int tid  = threadIdx.x;
  const int ks   = tid >> 6;          // wave = K-quarter
  const int lane = tid & 63;
  const int q    = lane >> 4;
  const int ln   = lane & 15;
  const int c0i  = ks * NCW;

  // ---- one-time LDS prep: packed reset bits + this block's bias rows
  for (int w = tid; w < 2 * T; w += NTHR) {
    const int t = w >> 1, half = (w & 1) * 32;
    unsigned v = 0;
#pragma unroll 8
    for (int i = 0; i < 32; ++i) v |= (unsigned)(reset[t * B + half + i] & 1) << i;
    rbits[w] = v;
  }
  if (tid < 64) lbias[tid] = bias[(tid >> 4) * H + col0 + (tid & 15)];

  // ---- preload this wave's weight fragments, PIN in regs
  u32x4 wreg[4][NCW];
#pragma unroll
  for (int g = 0; g < 4; ++g)
#pragma unroll
    for (int cc = 0; cc < NCW; ++cc) {
      const int c = c0i + cc;
      const u16* W = (c < NCX) ? wx : wh;
      const int stride = (c < NCX) ? KX : H;
      const int kk = ((c < NCX) ? c : c - NCX) * 32 + q * 8;
      wreg[g][cc] = *reinterpret_cast<const u32x4*>(
          W + (size_t)(g * H + col0 + ln) * stride + kk);
    }
#pragma unroll
  for (int g = 0; g < 4; ++g)
#pragma unroll
    for (int cc = 0; cc < NCW; ++cc)
      asm volatile("" : "+v"(wreg[g][cc]));   // opaque: no remat, must stay in regs

  // ---- cell-update state: thread owns one acc-quad = batches b0..b0+3, col cl
  const int b0 = (tid >> 4) * 4;
  const int cl = col0 + (tid & 15);
  float creg[4];
#pragma unroll
  for (int r = 0; r < 4; ++r)
    creg[r] = c0[(size_t)(b0 + r) * 2 * H + (size_t)L * H + cl];

  __syncthreads();
  float bval[4];
#pragma unroll
  for (int g = 0; g < 4; ++g) bval[g] = lbias[g * 16 + (tid & 15)];

  for (int s = 0; s <= T; ++s) {
    const bool active = (L == 0) ? (s < T) : (s >= 1);
    if (active) {
      const int t = (L == 0) ? s : s - 1;

      f32x4 acc[4][4];
#pragma unroll
      for (int g = 0; g < 4; ++g)
#pragma unroll
        for (int m = 0; m < 4; ++m) acc[g][m] = (f32x4){0.f, 0.f, 0.f, 0.f};

      const unsigned rw0 = rbits[2 * t], rw1 = rbits[2 * t + 1];
      const int rz[4] = {(int)((rw0 >> ln) & 1u), (int)((rw0 >> (16 + ln)) & 1u),
                         (int)((rw1 >> ln) & 1u), (int)((rw1 >> (16 + ln)) & 1u)};

      const u16* xsrc;
      if constexpr (L == 0) xsrc = xin + (size_t)t * B * D;
      else                  xsrc = xs1 + (size_t)((t + 1) & s1mask) * BH;
      const u16* hsrc = (L == 0) ? xs1 + (size_t)(s & s1mask) * BH
                                 : h1b + (size_t)(t & h1mask) * BH;

#pragma unroll
      for (int cc = 0; cc < NCW; ++cc) {
        const int c = c0i + cc;
        uint4 f[4];
        if (c < NCX) {                      // x part (no reset gating)
          const int kk = c * 32 + q * 8;
#pragma unroll
          for (int m = 0; m < 4; ++m)
            f[m] = *reinterpret_cast<const uint4*>(xsrc + (size_t)(16 * m + ln) * KX + kk);
        } else {                            // h part (reset zeroes state)
          const int kk = (c - NCX) * 32 + q * 8;
#pragma unroll
          for (int m = 0; m < 4; ++m) {
            uint4 v = *reinterpret_cast<const uint4*>(hsrc + (size_t)(16 * m + ln) * H + kk);
            f[m] = rz[m] ? make_uint4(0u, 0u, 0u, 0u) : v;
          }
        }
#pragma unroll
        for (int g = 0; g < 4; ++g)
#pragma unroll
          for (int m = 0; m < 4; ++m)
            acc[g][m] = mfma16(__builtin_bit_cast(bf16x8, f[m]),
                               __builtin_bit_cast(bf16x8, wreg[g][cc]), acc[g][m]);
      }

      // ---- dump partials: lane-consecutive f32x4 -> conflict-free ds_write_b128
#pragma unroll
      for (int g = 0; g < 4; ++g)
#pragma unroll
        for (int m = 0; m < 4; ++m)
          red[(g * 4 + ks) * 256 + m * 64 + q * 16 + ln] = acc[g][m];
      __syncthreads();

      // ---- reduce + cell update: thread tid owns cells (b0..b0+3, col cl)
      {
        f32x4 gate[4];
#pragma unroll
        for (int g = 0; g < 4; ++g) {
          f32x4 sum = red[(g * 4 + 0) * 256 + tid];
#pragma unroll
          for (int w = 1; w < 4; ++w) sum += red[(g * 4 + w) * 256 + tid];
          gate[g] = sum + (f32x4){bval[g], bval[g], bval[g], bval[g]};
        }
        const unsigned rstw = rbits[2 * t + (b0 >> 5)] >> (b0 & 31);
        float hv[4];
        u16 hb[4];
#pragma unroll
        for (int r = 0; r < 4; ++r) {
          float cp = ((rstw >> r) & 1u) ? 0.f : creg[r];
          float i_ = sigm(gate[0][r]);
          float f_ = sigm(gate[1][r]);
          float g_ = tanhf(gate[2][r]);
          float o_ = sigm(gate[3][r]);
          float cn = fmaf(f_, cp, i_ * g_);
          float hn = o_ * tanhf(cn);
          creg[r] = cn;
          hv[r] = hn;
          hb[r] = f2bf(hn);
        }
        u16* hdst = (L == 0)
            ? xs1 + (size_t)((s + 1) & s1mask) * BH
            : h1b + (size_t)((t + 1) & h1mask) * BH;
        // publish h: agent-scope WRITE-THROUGH u32 stores (at LLC once vmcnt==0).
        // Pack column pairs via lane^1 shuffle; even lanes store rows 0-1,
        // odd lanes rows 2-3.
#pragma unroll
        for (int r = 0; r < 4; ++r) {
          unsigned own = hb[r];
          unsigned oth = (unsigned)__shfl_xor((int)own, 1);
          unsigned pk = (tid & 1) ? ((oth & 0xffffu) | (own << 16))
                                  : (own | (oth << 16));
          if ((r >> 1) == (tid & 1))
            __hip_atomic_store(
                reinterpret_cast<unsigned*>(hdst + (size_t)(b0 + r) * H + (cl & ~1)),
                pk, __ATOMIC_RELAXED, __HIP_MEMORY_SCOPE_AGENT);
        }
        if constexpr (L == 1) {
#pragma unroll
          for (int r = 0; r < 4; ++r)
            __builtin_nontemporal_store(hv[r], &out[(size_t)t * BH + (size_t)(b0 + r) * H + cl]);
        }
        if (t == T - 1) {
#pragma unroll
          for (int r = 0; r < 4; ++r) {
            __builtin_nontemporal_store(
                hv[r], &out[OUT_HN + (size_t)(b0 + r) * 2 * H + (size_t)L * H + cl]);
            __builtin_nontemporal_store(
                creg[r], &out[OUT_CN + (size_t)(b0 + r) * 2 * H + (size_t)L * H + cl]);
          }
        }
      }
    }

    // ---- barrier:
    //   sync#1 : s_waitcnt vmcnt(0) in every wave -> our agent h-stores are at LLC
    //   flag   : one relaxed agent STORE per block (no RMW, no line contention)
    //   poll   : threads 0..127 each watch one block's flag; in full mode L0
    //            ignores L1 flags entirely (monotonic buffers -> no WAR hazard)
    //   fence  : fallback mode only (ring reuse needs L1/L2 invalidate)
    if (s < T) {
      __syncthreads();
      if (tid == 0)
        __hip_atomic_store(&flags[blockIdx.x], s + 1,
                           __ATOMIC_RELAXED, __HIP_MEMORY_SCOPE_AGENT);
      const bool skip = full && (L == 0) && (tid >= 64);
      if (tid < NBLK && !skip) {
        while (__hip_atomic_load(&flags[tid], __ATOMIC_RELAXED,
                                 __HIP_MEMORY_SCOPE_AGENT) < s + 1)
          __builtin_amdgcn_s_sleep(1);
      }
      if (!full && tid == 0)
        __builtin_amdgcn_fence(__ATOMIC_ACQUIRE, "agent");   // buffer_inv (fallback)
      __syncthreads();
    }
  }
}

__global__ void __launch_bounds__(NTHR, 1) lstm_seq(
    const u16* __restrict__ xin,
    const u16* __restrict__ wx0, const u16* __restrict__ wh0,
    const u16* __restrict__ wx1, const u16* __restrict__ wh1,
    const float* __restrict__ bias0, const float* __restrict__ bias1,
    u16* __restrict__ xs1, u16* __restrict__ h1b,
    const float* __restrict__ c0, const int* __restrict__ reset,
    float* __restrict__ out, int* __restrict__ flags,
    int s1mask, int h1mask, int full) {
  __shared__ f32x4 red[4 * 4 * 256];      // 64 KB partials
  __shared__ unsigned rbits[2 * T];       // 2 KB packed reset bits
  __shared__ float lbias[64];             // this block's 64 bias rows
  const int group = blockIdx.x >> 6;
  const int col0 = (blockIdx.x & 63) << 4;
  if (group == 0)
    run_layer<0>(xin, wx0, wh0, bias0, xs1, h1b, c0, reset, out, flags, col0,
                 red, rbits, lbias, s1mask, h1mask, full);
  else
    run_layer<1>(nullptr, wx1, wh1, bias1, xs1, h1b, c0, reset, out, flags, col0,
                 red, rbits, lbias, s1mask, h1mask, full);
}

extern "C" void kernel_launch(void* const* d_in, const int* in_sizes, int n_in,
                              void* d_out, int out_size, void* d_ws, size_t ws_size,
                              hipStream_t stream) {
  (void)in_sizes; (void)n_in; (void)out_size;
  const float* input = (const float*)d_in[0];
  const int*   reset = (const int*)d_in[1];
  const float* h0    = (const float*)d_in[2];
  const float* c0    = (const float*)d_in[3];
  const float* Wih0  = (const float*)d_in[4];
  const float* Whh0  = (const float*)d_in[5];
  const float* bih0  = (const float*)d_in[6];
  const float* bhh0  = (const float*)d_in[7];
  const float* Wih1  = (const float*)d_in[8];
  const float* Whh1  = (const float*)d_in[9];
  const float* bih1  = (const float*)d_in[10];
  const float* bhh1  = (const float*)d_in[11];
  float* out = (float*)d_out;
  char* ws = (char*)d_ws;

  const size_t SLOT = (size_t)B * H * 2;             // one [B][H] bf16 slab (128 KB)
  const size_t FIXED = (size_t)G4 * D * 2 + 3 * (size_t)G4 * H * 2   // weights
                     + (size_t)T * B * D * 2                          // xin
                     + 2 * (size_t)G4 * 4 + 4096;                     // biases + flags + pad
  const bool full = ws_size >= FIXED + 2 * (size_t)(T + 1) * SLOT + 65536;
  const int d0 = full ? (T + 1) : 4;   // xs1 slots
  const int d1 = full ? (T + 1) : 2;   // h1b slots
  const int s1mask = full ? 511 : 3;   // t+1 <= 256 < 512: mask is identity in full mode
  const int h1mask = full ? 511 : 1;

  size_t off = 0;
  auto alloc = [&](size_t bytes) { size_t o = off; off += (bytes + 255) & ~(size_t)255; return o; };
  u16* wx0 = (u16*)(ws + alloc((size_t)G4 * D * 2));
  u16* wh0 = (u16*)(ws + alloc((size_t)G4 * H * 2));
  u16* wx1 = (u16*)(ws + alloc((size_t)G4 * H * 2));
  u16* wh1 = (u16*)(ws + alloc((size_t)G4 * H * 2));
  u16* xin = (u16*)(ws + alloc((size_t)T * B * D * 2));
  u16* xs1 = (u16*)(ws + alloc((size_t)d0 * SLOT));
  u16* h1b = (u16*)(ws + alloc((size_t)d1 * SLOT));
  float* pb0 = (float*)(ws + alloc((size_t)G4 * 4));
  float* pb1 = (float*)(ws + alloc((size_t)G4 * 4));
  int* flg = (int*)(ws + alloc(512));

  cvt_bf16<<<1024, 256, 0, stream>>>(Wih0, wx0, G4 * D / 4);
  cvt_bf16<<<1024, 256, 0, stream>>>(Whh0, wh0, G4 * H / 4);
  cvt_bf16<<<1024, 256, 0, stream>>>(Wih1, wx1, G4 * H / 4);
  cvt_bf16<<<1024, 256, 0, stream>>>(Whh1, wh1, G4 * H / 4);
  cvt_bf16<<<2048, 256, 0, stream>>>(input, xin, T * B * D / 4);
  init_state<<<512, 256, 0, stream>>>(h0, xs1, h1b, bih0, bhh0, bih1, bhh1, pb0, pb1, flg);
  lstm_seq<<<NBLK, NTHR, 0, stream>>>(xin, wx0, wh0, wx1, wh1, pb0, pb1,
                                      xs1, h1b, c0, reset, out, flg,
                                      s1mask, h1mask, full ? 1 : 0);
}

// Round 3
// 2079.327 us; speedup vs baseline: 2.1616x; 1.6972x over previous
//
#include <hip/hip_runtime.h>

typedef __bf16 bf16x8 __attribute__((ext_vector_type(8)));
typedef float f32x4 __attribute__((ext_vector_type(4)));
typedef unsigned u32x4 __attribute__((ext_vector_type(4)));
typedef unsigned short u16;

constexpr int T = 256, B = 64, D = 512, H = 1024;
constexpr int G4 = 4 * H;
constexpr int NBLK = 256;   // 2 layers x 2 batch-halves x 64 col-blocks (1/CU, full chip)
constexpr int NTHR = 256;   // 4 waves; wave = one K-quarter, all 4 gates
constexpr int BS = 32;      // batches per block (2-way batch split)
constexpr int MT = 2;       // 16-row MFMA tiles per block (BS/16)

__device__ __forceinline__ u16 f2bf(float f) {
  unsigned u = __builtin_bit_cast(unsigned, f);
  u += 0x7fffu + ((u >> 16) & 1u);
  return (u16)(u >> 16);
}

__device__ __forceinline__ f32x4 mfma16(bf16x8 a, bf16x8 b, f32x4 c) {
  return __builtin_amdgcn_mfma_f32_16x16x32_bf16(a, b, c, 0, 0, 0);
}

__device__ __forceinline__ float sigm(float x) { return 1.f / (1.f + expf(-x)); }

__device__ __forceinline__ int ldflag(const int* f, int i) {
  return __hip_atomic_load(&f[i], __ATOMIC_RELAXED, __HIP_MEMORY_SCOPE_AGENT);
}

// ---------------- prep kernels ----------------
__global__ void cvt_bf16(const float* __restrict__ src, u16* __restrict__ dst, int n4) {
  int i = blockIdx.x * blockDim.x + threadIdx.x;
  int st = gridDim.x * blockDim.x;
  for (; i < n4; i += st) {
    float4 v = reinterpret_cast<const float4*>(src)[i];
    ushort4 o;
    o.x = f2bf(v.x); o.y = f2bf(v.y); o.z = f2bf(v.z); o.w = f2bf(v.w);
    reinterpret_cast<ushort4*>(dst)[i] = o;
  }
}

__global__ void init_state(const float* __restrict__ h0,
                           u16* __restrict__ xs1, u16* __restrict__ h1buf,
                           const float* __restrict__ bih0, const float* __restrict__ bhh0,
                           const float* __restrict__ bih1, const float* __restrict__ bhh1,
                           float* __restrict__ bias0, float* __restrict__ bias1,
                           int* __restrict__ flags) {
  int i = blockIdx.x * blockDim.x + threadIdx.x;
  if (i < NBLK) flags[i] = 0;              // per-block step flags (replay-safe reset)
  if (i < 2 * B * H) {
    int l = i / (B * H), rem = i % (B * H);
    int b = rem / H, k = rem % H;
    u16 v = f2bf(h0[(size_t)b * 2 * H + (size_t)l * H + k]);
    if (l == 0) xs1[(size_t)b * H + k] = v;   // slot 0 = initial h for layer0
    else        h1buf[(size_t)b * H + k] = v; // slot 0 = initial h for layer1
  }
  if (i < G4) {
    bias0[i] = bih0[i] + bhh0[i];
    bias1[i] = bih1[i] + bhh1[i];
  }
}

// ---------------- persistent pipelined LSTM ----------------
// Block = (layer L, batch-half, 16 h-columns). 256 blocks -> whole chip.
// Wave ks (0..3) owns a K-quarter of both the x-part and h-part chunks;
// weights pinned in AGPRs (MFMA reads B from AGPR; frees VGPRs for deep
// load pipelining).
//
// Full (monotonic) mode: h history is virgin-per-step (write-through agent
// stores -> LLC); fetched-only-after-flag lines can't be stale -> PLAIN
// fragment loads, no fences. Dependency sets: L0(half) waits only its own
// 64-block group; L1(half) waits L0(half) [x, usually pre-satisfied since
// L0 runs ahead] and L1(half) [h, polled AFTER the x-part MFMAs so
// straggler wait overlaps compute].
// Fallback (small ws): ring slots + unified 4-group poll + acquire fence.
template <int L>
__device__ __forceinline__ void run_layer(
    const u16* __restrict__ xin, const u16* __restrict__ wx, const u16* __restrict__ wh,
    const float* __restrict__ bias, u16* __restrict__ xs1, u16* __restrict__ h1b,
    const float* __restrict__ c0, const int* __restrict__ reset,
    float* __restrict__ out, int* __restrict__ flags, int half, int col0,
    f32x4* __restrict__ red, unsigned* __restrict__ rbits, float* __restrict__ lbias,
    const int s1mask, const int h1mask, const int full) {
  constexpr int KX   = L ? H : D;       // x-part K
  constexpr int NCX  = KX / 32;         // x chunks (16 or 32)
  constexpr int NCXW = NCX / 4;         // x chunks per wave (4 or 8)
  constexpr int NHW  = (H / 32) / 4;    // h chunks per wave (8)
  constexpr int NCW  = NCXW + NHW;      // weight chunks per wave (12 or 16)
  const size_t BH = (size_t)B * H;
  const size_t OUT_HN = (size_t)T * BH;
  const size_t OUT_CN = OUT_HN + 2 * BH;

  const int tid  = threadIdx.x;
  const int ks   = tid >> 6;            // wave = K-quarter
  const int lane = tid & 63;
  const int q    = lane >> 4;
  const int ln   = lane & 15;

  // ---- one-time LDS prep: this half's packed reset bits + bias rows
  for (int t = tid; t < T; t += NTHR) {
    unsigned v = 0;
#pragma unroll 8
    for (int i = 0; i < 32; ++i)
      v |= (unsigned)(reset[t * B + half * BS + i] & 1) << i;
    rbits[t] = v;
  }
  if (tid < 64) lbias[tid] = bias[(tid >> 4) * H + col0 + (tid & 15)];

  // ---- preload this wave's weight fragments, pin in AGPRs
  u32x4 wreg[4][NCW];
#pragma unroll
  for (int g = 0; g < 4; ++g)
#pragma unroll
    for (int cc = 0; cc < NCW; ++cc) {
      const bool isx = cc < NCXW;
      const int c = isx ? ks * NCXW + cc : ks * NHW + (cc - NCXW);
      const u16* W = isx ? wx : wh;
      const int stride = isx ? KX : H;
      const int kk = c * 32 + q * 8;
      wreg[g][cc] = *reinterpret_cast<const u32x4*>(
          W + (size_t)(g * H + col0 + ln) * stride + kk);
    }
#pragma unroll
  for (int g = 0; g < 4; ++g)
#pragma unroll
    for (int cc = 0; cc < NCW; ++cc)
      asm volatile("" : "+a"(wreg[g][cc]));   // opaque + AGPR class: stays resident,
                                              // VGPRs freed for load pipelining

  // ---- cell-update state: thread (tid<128) owns batches b0..b0+3, col cl
  const int b0l = (tid >> 4) * 4;       // local batch base (valid tid<128)
  const int cl  = col0 + (tid & 15);
  float creg[4] = {0.f, 0.f, 0.f, 0.f};
  if (tid < 128)
#pragma unroll
    for (int r = 0; r < 4; ++r)
      creg[r] = c0[(size_t)(half * BS + b0l + r) * 2 * H + (size_t)L * H + cl];

  __syncthreads();
  float bval[4];
#pragma unroll
  for (int g = 0; g < 4; ++g) bval[g] = lbias[g * 16 + (tid & 15)];

  float hv[4] = {0.f, 0.f, 0.f, 0.f};   // carried into tail for deferred out stores

  for (int s = 0; s <= T; ++s) {
    const bool active = (L == 0) ? (s < T) : (s >= 1);
    const int t = (L == 0) ? s : s - 1;
    if (active) {
      // ---- x-availability poll (every wave polls independently; no barrier)
      if (full) {
        if (L == 1) {   // need L0(half) done iter s-1 -> xs1[s] ready (usually instant)
          while (ldflag(flags, half * 64 + lane) < s) __builtin_amdgcn_s_sleep(1);
        }
      } else {          // unified full-grid poll + acquire (ring mode)
        for (;;) {
          int a = ldflag(flags, lane),       b = ldflag(flags, 64 + lane);
          int c = ldflag(flags, 128 + lane), d = ldflag(flags, 192 + lane);
          int m1 = a < b ? a : b, m2 = c < d ? c : d;
          if ((m1 < m2 ? m1 : m2) >= s) break;
          __builtin_amdgcn_s_sleep(1);
        }
        __builtin_amdgcn_fence(__ATOMIC_ACQUIRE, "agent");   // buffer_inv
      }

      f32x4 acc[4][MT];
#pragma unroll
      for (int g = 0; g < 4; ++g)
#pragma unroll
        for (int m = 0; m < MT; ++m) acc[g][m] = (f32x4){0.f, 0.f, 0.f, 0.f};

      // ---- x-part (no reset gating; overlaps other blocks' h publication)
      const u16* xsrc = (L == 0) ? xin + (size_t)t * B * D
                                 : xs1 + (size_t)(s & s1mask) * BH;
#pragma unroll
      for (int cc = 0; cc < NCXW; ++cc) {
        const int kk = (ks * NCXW + cc) * 32 + q * 8;
        uint4 f[MT];
#pragma unroll
        for (int m = 0; m < MT; ++m)
          f[m] = *reinterpret_cast<const uint4*>(
              xsrc + (size_t)(half * BS + 16 * m + ln) * KX + kk);
#pragma unroll
        for (int g = 0; g < 4; ++g)
#pragma unroll
          for (int m = 0; m < MT; ++m)
            acc[g][m] = mfma16(__builtin_bit_cast(bf16x8, f[m]),
                               __builtin_bit_cast(bf16x8, wreg[g][cc]), acc[g][m]);
      }

      // ---- own-group h poll (after x-part: straggler wait overlaps compute)
      if (full) {
        const int gbase = L * 128 + half * 64;
        while (ldflag(flags, gbase + lane) < s) __builtin_amdgcn_s_sleep(1);
      }

      // ---- h-part (reset zeroes recurrent state rows)
      const unsigned rw = rbits[t];
      const int rz0 = (int)((rw >> ln) & 1u);
      const int rz1 = (int)((rw >> (16 + ln)) & 1u);
      const u16* hsrc = (L == 0) ? xs1 + (size_t)(s & s1mask) * BH
                                 : h1b + (size_t)(t & h1mask) * BH;
#pragma unroll
      for (int cc = 0; cc < NHW; ++cc) {
        const int kk = (ks * NHW + cc) * 32 + q * 8;
        uint4 f[MT];
        f[0] = *reinterpret_cast<const uint4*>(
            hsrc + (size_t)(half * BS + ln) * H + kk);
        f[1] = *reinterpret_cast<const uint4*>(
            hsrc + (size_t)(half * BS + 16 + ln) * H + kk);
        if (rz0) f[0] = make_uint4(0u, 0u, 0u, 0u);
        if (rz1) f[1] = make_uint4(0u, 0u, 0u, 0u);
#pragma unroll
        for (int g = 0; g < 4; ++g)
#pragma unroll
          for (int m = 0; m < MT; ++m)
            acc[g][m] = mfma16(__builtin_bit_cast(bf16x8, f[m]),
                               __builtin_bit_cast(bf16x8, wreg[g][NCXW + cc]), acc[g][m]);
      }

      // ---- dump partials: lane-consecutive f32x4 -> conflict-free ds_write_b128
#pragma unroll
      for (int g = 0; g < 4; ++g)
#pragma unroll
        for (int m = 0; m < MT; ++m)
          red[(g * 4 + ks) * (MT * 64) + m * 64 + lane] = acc[g][m];
      __syncthreads();

      // ---- reduce + cell update: threads 0..127 own (batch-quad, col)
      if (tid < 128) {
        f32x4 gate[4];
#pragma unroll
        for (int g = 0; g < 4; ++g) {
          f32x4 sum = red[(g * 4 + 0) * (MT * 64) + tid];
#pragma unroll
          for (int w = 1; w < 4; ++w) sum += red[(g * 4 + w) * (MT * 64) + tid];
          gate[g] = sum + (f32x4){bval[g], bval[g], bval[g], bval[g]};
        }
        const unsigned rstw = rbits[t] >> b0l;
        u16 hb[4];
#pragma unroll
        for (int r = 0; r < 4; ++r) {
          float cp = ((rstw >> r) & 1u) ? 0.f : creg[r];
          float i_ = sigm(gate[0][r]);
          float f_ = sigm(gate[1][r]);
          float g_ = tanhf(gate[2][r]);
          float o_ = sigm(gate[3][r]);
          float cn = fmaf(f_, cp, i_ * g_);
          float hn = o_ * tanhf(cn);
          creg[r] = cn;
          hv[r] = hn;
          hb[r] = f2bf(hn);
        }
        u16* hdst = (L == 0)
            ? xs1 + (size_t)((s + 1) & s1mask) * BH
            : h1b + (size_t)((t + 1) & h1mask) * BH;
        // publish h: agent-scope WRITE-THROUGH u32 stores (at LLC once vmcnt==0).
        // Pack column pairs via lane^1 shuffle; even lanes rows 0-1, odd rows 2-3.
#pragma unroll
        for (int r = 0; r < 4; ++r) {
          unsigned own = hb[r];
          unsigned oth = (unsigned)__shfl_xor((int)own, 1);
          unsigned pk = (tid & 1) ? ((oth & 0xffffu) | (own << 16))
                                  : (own | (oth << 16));
          if ((r >> 1) == (tid & 1))
            __hip_atomic_store(
                reinterpret_cast<unsigned*>(
                    hdst + (size_t)(half * BS + b0l + r) * H + (cl & ~1)),
                pk, __ATOMIC_RELAXED, __HIP_MEMORY_SCOPE_AGENT);
        }
        if (t == T - 1) {   // final states; L1 also emits its last out row here
#pragma unroll
          for (int r = 0; r < 4; ++r) {
            const size_t brow = (size_t)(half * BS + b0l + r);
            __builtin_nontemporal_store(
                hv[r], &out[OUT_HN + brow * 2 * H + (size_t)L * H + cl]);
            __builtin_nontemporal_store(
                creg[r], &out[OUT_CN + brow * 2 * H + (size_t)L * H + cl]);
            if (L == 1)
              __builtin_nontemporal_store(
                  hv[r], &out[(size_t)t * BH + brow * H + cl]);
          }
        }
      }
    }

    // ---- tail: drain publish stores, post flag, then (off critical path)
    // emit this step's out rows so their HBM drain overlaps the next poll.
    if (s < T) {
      __syncthreads();   // vmcnt(0) per wave: h stores are at LLC
      if (tid == 0)
        __hip_atomic_store(&flags[blockIdx.x], s + 1,
                           __ATOMIC_RELAXED, __HIP_MEMORY_SCOPE_AGENT);
      if (L == 1 && active && t < T - 1 && tid < 128) {
#pragma unroll
        for (int r = 0; r < 4; ++r)
          __builtin_nontemporal_store(
              hv[r], &out[(size_t)t * BH + (size_t)(half * BS + b0l + r) * H + cl]);
      }
    }
  }
}

__global__ void __launch_bounds__(NTHR, 1) lstm_seq(
    const u16* __restrict__ xin,
    const u16* __restrict__ wx0, const u16* __restrict__ wh0,
    const u16* __restrict__ wx1, const u16* __restrict__ wh1,
    const float* __restrict__ bias0, const float* __restrict__ bias1,
    u16* __restrict__ xs1, u16* __restrict__ h1b,
    const float* __restrict__ c0, const int* __restrict__ reset,
    float* __restrict__ out, int* __restrict__ flags,
    int s1mask, int h1mask, int full) {
  __shared__ f32x4 red[4 * 4 * MT * 64];  // 32 KB partials
  __shared__ unsigned rbits[T];           // 1 KB packed reset bits (this half)
  __shared__ float lbias[64];             // this block's 64 bias rows
  // blockIdx = L*128 + half*64 + colblk
  const int group = blockIdx.x >> 7;
  const int half  = (blockIdx.x >> 6) & 1;
  const int col0  = (blockIdx.x & 63) << 4;
  if (group == 0)
    run_layer<0>(xin, wx0, wh0, bias0, xs1, h1b, c0, reset, out, flags, half, col0,
                 red, rbits, lbias, s1mask, h1mask, full);
  else
    run_layer<1>(nullptr, wx1, wh1, bias1, xs1, h1b, c0, reset, out, flags, half, col0,
                 red, rbits, lbias, s1mask, h1mask, full);
}

extern "C" void kernel_launch(void* const* d_in, const int* in_sizes, int n_in,
                              void* d_out, int out_size, void* d_ws, size_t ws_size,
                              hipStream_t stream) {
  (void)in_sizes; (void)n_in; (void)out_size;
  const float* input = (const float*)d_in[0];
  const int*   reset = (const int*)d_in[1];
  const float* h0    = (const float*)d_in[2];
  const float* c0    = (const float*)d_in[3];
  const float* Wih0  = (const float*)d_in[4];
  const float* Whh0  = (const float*)d_in[5];
  const float* bih0  = (const float*)d_in[6];
  const float* bhh0  = (const float*)d_in[7];
  const float* Wih1  = (const float*)d_in[8];
  const float* Whh1  = (const float*)d_in[9];
  const float* bih1  = (const float*)d_in[10];
  const float* bhh1  = (const float*)d_in[11];
  float* out = (float*)d_out;
  char* ws = (char*)d_ws;

  const size_t SLOT = (size_t)B * H * 2;             // one [B][H] bf16 slab (128 KB)
  const size_t FIXED = (size_t)G4 * D * 2 + 3 * (size_t)G4 * H * 2   // weights
                     + (size_t)T * B * D * 2                          // xin
                     + 2 * (size_t)G4 * 4 + 4096;                     // biases + flags + pad
  const bool full = ws_size >= FIXED + 2 * (size_t)(T + 1) * SLOT + 65536;
  const int d0 = full ? (T + 1) : 4;   // xs1 slots
  const int d1 = full ? (T + 1) : 2;   // h1b slots
  const int s1mask = full ? 511 : 3;   // slot index <= 256 < 512: identity in full mode
  const int h1mask = full ? 511 : 1;

  size_t off = 0;
  auto alloc = [&](size_t bytes) { size_t o = off; off += (bytes + 255) & ~(size_t)255; return o; };
  u16* wx0 = (u16*)(ws + alloc((size_t)G4 * D * 2));
  u16* wh0 = (u16*)(ws + alloc((size_t)G4 * H * 2));
  u16* wx1 = (u16*)(ws + alloc((size_t)G4 * H * 2));
  u16* wh1 = (u16*)(ws + alloc((size_t)G4 * H * 2));
  u16* xin = (u16*)(ws + alloc((size_t)T * B * D * 2));
  u16* xs1 = (u16*)(ws + alloc((size_t)d0 * SLOT));
  u16* h1b = (u16*)(ws + alloc((size_t)d1 * SLOT));
  float* pb0 = (float*)(ws + alloc((size_t)G4 * 4));
  float* pb1 = (float*)(ws + alloc((size_t)G4 * 4));
  int* flg = (int*)(ws + alloc(1024));

  cvt_bf16<<<1024, 256, 0, stream>>>(Wih0, wx0, G4 * D / 4);
  cvt_bf16<<<1024, 256, 0, stream>>>(Whh0, wh0, G4 * H / 4);
  cvt_bf16<<<1024, 256, 0, stream>>>(Wih1, wx1, G4 * H / 4);
  cvt_bf16<<<1024, 256, 0, stream>>>(Whh1, wh1, G4 * H / 4);
  cvt_bf16<<<2048, 256, 0, stream>>>(input, xin, T * B * D / 4);
  init_state<<<512, 256, 0, stream>>>(h0, xs1, h1b, bih0, bhh0, bih1, bhh1, pb0, pb1, flg);
  lstm_seq<<<NBLK, NTHR, 0, stream>>>(xin, wx0, wh0, wx1, wh1, pb0, pb1,
                                      xs1, h1b, c0, reset, out, flg,
                                      s1mask, h1mask, full ? 1 : 0);
}

// Round 4
// 1955.055 us; speedup vs baseline: 2.2990x; 1.0636x over previous
//
#include <hip/hip_runtime.h>

typedef __bf16 bf16x8 __attribute__((ext_vector_type(8)));
typedef float f32x4 __attribute__((ext_vector_type(4)));
typedef unsigned u32x4 __attribute__((ext_vector_type(4)));
typedef unsigned short u16;

constexpr int T = 256, B = 64, D = 512, H = 1024;
constexpr int G4 = 4 * H;
constexpr int NBLK = 256;   // 2 layers x 2 batch-halves x 64 col-blocks (1/CU, full chip)
constexpr int NTHR = 256;   // 4 waves; wave = one K-quarter, all 4 gates
constexpr int BS = 32;      // batches per block (2-way batch split)
constexpr int MT = 2;       // 16-row MFMA tiles per block (BS/16)

__device__ __forceinline__ u16 f2bf(float f) {
  unsigned u = __builtin_bit_cast(unsigned, f);
  u += 0x7fffu + ((u >> 16) & 1u);
  return (u16)(u >> 16);
}

__device__ __forceinline__ f32x4 mfma16(bf16x8 a, bf16x8 b, f32x4 c) {
  return __builtin_amdgcn_mfma_f32_16x16x32_bf16(a, b, c, 0, 0, 0);
}

__device__ __forceinline__ float sigm(float x) { return 1.f / (1.f + expf(-x)); }

__device__ __forceinline__ int ldflag(const int* f, int i) {
  return __hip_atomic_load(&f[i], __ATOMIC_RELAXED, __HIP_MEMORY_SCOPE_AGENT);
}

// ---------------- prep kernels ----------------
__global__ void cvt_bf16(const float* __restrict__ src, u16* __restrict__ dst, int n4) {
  int i = blockIdx.x * blockDim.x + threadIdx.x;
  int st = gridDim.x * blockDim.x;
  for (; i < n4; i += st) {
    float4 v = reinterpret_cast<const float4*>(src)[i];
    ushort4 o;
    o.x = f2bf(v.x); o.y = f2bf(v.y); o.z = f2bf(v.z); o.w = f2bf(v.w);
    reinterpret_cast<ushort4*>(dst)[i] = o;
  }
}

__global__ void init_state(const float* __restrict__ h0,
                           u16* __restrict__ xs1, u16* __restrict__ h1buf,
                           const float* __restrict__ bih0, const float* __restrict__ bhh0,
                           const float* __restrict__ bih1, const float* __restrict__ bhh1,
                           float* __restrict__ bias0, float* __restrict__ bias1,
                           int* __restrict__ flags) {
  int i = blockIdx.x * blockDim.x + threadIdx.x;
  if (i < NBLK) flags[i] = 0;              // per-block step flags (replay-safe reset)
  if (i < 2 * B * H) {
    int l = i / (B * H), rem = i % (B * H);
    int b = rem / H, k = rem % H;
    u16 v = f2bf(h0[(size_t)b * 2 * H + (size_t)l * H + k]);
    if (l == 0) xs1[(size_t)b * H + k] = v;   // slot 0 = initial h for layer0
    else        h1buf[(size_t)b * H + k] = v; // slot 0 = initial h for layer1
  }
  if (i < G4) {
    bias0[i] = bih0[i] + bhh0[i];
    bias1[i] = bih1[i] + bhh1[i];
  }
}

// ---------------- persistent pipelined LSTM ----------------
// Block = (layer L, batch-half, 16 h-columns). 256 blocks -> whole chip.
// Wave ks (0..3) owns a K-quarter; weights pinned in AGPRs.
//
// Per-step schedule (full/monotonic mode):
//   head : own-group h poll -> membar -> BURST-issue all h fragment loads
//          -> x MFMAs from PREFETCHED regs (hides h LLC round trip)
//          -> h MFMAs -> LDS dump -> reduce/cell -> write-through h publish
//   tail : syncthreads (vmcnt drain) -> post flag -> deferred out stores
//          -> PREFETCH next step's x fragments into regs
//            (L0: xin, no dependency; L1: poll L0 flag >= s+1, usually instant
//             since L0's chain is strictly shorter and it never waits on L1)
// Coherence: h history is virgin-per-step (write-through agent stores -> LLC);
// lines fetched only after the producer's flag can't be stale -> PLAIN loads,
// no fences in the loop.
// Fallback (small ws): ring slots + unified 4-group poll + acquire fence,
// x loaded in-loop after the fence.
template <int L>
__device__ __forceinline__ void run_layer(
    const u16* __restrict__ xin, const u16* __restrict__ wx, const u16* __restrict__ wh,
    const float* __restrict__ bias, u16* __restrict__ xs1, u16* __restrict__ h1b,
    const float* __restrict__ c0, const int* __restrict__ reset,
    float* __restrict__ out, int* __restrict__ flags, int half, int col0,
    f32x4* __restrict__ red, unsigned* __restrict__ rbits, float* __restrict__ lbias,
    const int s1mask, const int h1mask, const int full) {
  constexpr int KX   = L ? H : D;       // x-part K
  constexpr int NCX  = KX / 32;         // x chunks (16 or 32)
  constexpr int NCXW = NCX / 4;         // x chunks per wave (4 or 8)
  constexpr int NHW  = (H / 32) / 4;    // h chunks per wave (8)
  constexpr int NCW  = NCXW + NHW;      // weight chunks per wave (12 or 16)
  const size_t BH = (size_t)B * H;
  const size_t OUT_HN = (size_t)T * BH;
  const size_t OUT_CN = OUT_HN + 2 * BH;

  const int tid  = threadIdx.x;
  const int ks   = tid >> 6;            // wave = K-quarter
  const int lane = tid & 63;
  const int q    = lane >> 4;
  const int ln   = lane & 15;

  // ---- one-time LDS prep: this half's packed reset bits + bias rows
  for (int t = tid; t < T; t += NTHR) {
    unsigned v = 0;
#pragma unroll 8
    for (int i = 0; i < 32; ++i)
      v |= (unsigned)(reset[t * B + half * BS + i] & 1) << i;
    rbits[t] = v;
  }
  if (tid < 64) lbias[tid] = bias[(tid >> 4) * H + col0 + (tid & 15)];

  // ---- preload this wave's weight fragments, pin in AGPRs
  u32x4 wreg[4][NCW];
#pragma unroll
  for (int g = 0; g < 4; ++g)
#pragma unroll
    for (int cc = 0; cc < NCW; ++cc) {
      const bool isx = cc < NCXW;
      const int c = isx ? ks * NCXW + cc : ks * NHW + (cc - NCXW);
      const u16* W = isx ? wx : wh;
      const int stride = isx ? KX : H;
      const int kk = c * 32 + q * 8;
      wreg[g][cc] = *reinterpret_cast<const u32x4*>(
          W + (size_t)(g * H + col0 + ln) * stride + kk);
    }
#pragma unroll
  for (int g = 0; g < 4; ++g)
#pragma unroll
    for (int cc = 0; cc < NCW; ++cc)
      asm volatile("" : "+a"(wreg[g][cc]));   // opaque + AGPR class: stays resident,
                                              // VGPRs freed for load pipelining

  // ---- cell-update state: thread (tid<128) owns batches b0..b0+3, col cl
  const int b0l = (tid >> 4) * 4;       // local batch base (valid tid<128)
  const int cl  = col0 + (tid & 15);
  float creg[4] = {0.f, 0.f, 0.f, 0.f};
  if (tid < 128)
#pragma unroll
    for (int r = 0; r < 4; ++r)
      creg[r] = c0[(size_t)(half * BS + b0l + r) * 2 * H + (size_t)L * H + cl];

  __syncthreads();
  float bval[4];
#pragma unroll
  for (int g = 0; g < 4; ++g) bval[g] = lbias[g * 16 + (tid & 15)];

  float hv[4] = {0.f, 0.f, 0.f, 0.f};   // carried into tail for deferred out stores

  // x-fragment prefetch registers (persist across iterations; static indexing only)
  uint4 xf[NCXW][MT];
  auto load_xfrags = [&](const u16* xsrc) {
#pragma unroll
    for (int cc = 0; cc < NCXW; ++cc) {
      const int kk = (ks * NCXW + cc) * 32 + q * 8;
#pragma unroll
      for (int m = 0; m < MT; ++m)
        xf[cc][m] = *reinterpret_cast<const uint4*>(
            xsrc + (size_t)(half * BS + 16 * m + ln) * KX + kk);
    }
  };
  if (full && L == 0) load_xfrags(xin);   // prologue prefetch for t=0
  // (full-mode L1: s=0 is inactive; its tail does the first prefetch)

  for (int s = 0; s <= T; ++s) {
    const bool active = (L == 0) ? (s < T) : (s >= 1);
    const int t = (L == 0) ? s : s - 1;
    if (active) {
      // ---- own-group h availability poll
      if (full) {
        const int gbase = L * 128 + half * 64;
        while (ldflag(flags, gbase + lane) < s) __builtin_amdgcn_s_sleep(1);
        asm volatile("" ::: "memory");   // no load hoisting above the poll
      } else {                           // unified full-grid poll + acquire (ring mode)
        for (;;) {
          int a = ldflag(flags, lane),       b = ldflag(flags, 64 + lane);
          int c = ldflag(flags, 128 + lane), d = ldflag(flags, 192 + lane);
          int m1 = a < b ? a : b, m2 = c < d ? c : d;
          if ((m1 < m2 ? m1 : m2) >= s) break;
          __builtin_amdgcn_s_sleep(1);
        }
        __builtin_amdgcn_fence(__ATOMIC_ACQUIRE, "agent");   // buffer_inv
        asm volatile("" ::: "memory");
        const u16* xsrc = (L == 0) ? xin + (size_t)t * B * D
                                   : xs1 + (size_t)(s & s1mask) * BH;
        load_xfrags(xsrc);               // fallback: x loaded in-loop, post-fence
      }

      // ---- BURST-issue all h fragment loads (one LLC round trip, max overlap)
      const u16* hsrc = (L == 0) ? xs1 + (size_t)(s & s1mask) * BH
                                 : h1b + (size_t)(t & h1mask) * BH;
      uint4 hf[NHW][MT];
#pragma unroll
      for (int cc = 0; cc < NHW; ++cc) {
        const int kk = (ks * NHW + cc) * 32 + q * 8;
#pragma unroll
        for (int m = 0; m < MT; ++m)
          hf[cc][m] = *reinterpret_cast<const uint4*>(
              hsrc + (size_t)(half * BS + 16 * m + ln) * H + kk);
      }

      f32x4 acc[4][MT];
#pragma unroll
      for (int g = 0; g < 4; ++g)
#pragma unroll
        for (int m = 0; m < MT; ++m) acc[g][m] = (f32x4){0.f, 0.f, 0.f, 0.f};

      // ---- x MFMAs from prefetched regs (run while h loads are in flight)
#pragma unroll
      for (int cc = 0; cc < NCXW; ++cc)
#pragma unroll
        for (int g = 0; g < 4; ++g)
#pragma unroll
          for (int m = 0; m < MT; ++m)
            acc[g][m] = mfma16(__builtin_bit_cast(bf16x8, xf[cc][m]),
                               __builtin_bit_cast(bf16x8, wreg[g][cc]), acc[g][m]);

      // ---- h MFMAs (reset zeroes recurrent state rows)
      const unsigned rw = rbits[t];
      const int rz0 = (int)((rw >> ln) & 1u);
      const int rz1 = (int)((rw >> (16 + ln)) & 1u);
      const uint4 zz = make_uint4(0u, 0u, 0u, 0u);
#pragma unroll
      for (int cc = 0; cc < NHW; ++cc) {
        const uint4 v0 = rz0 ? zz : hf[cc][0];
        const uint4 v1 = rz1 ? zz : hf[cc][1];
#pragma unroll
        for (int g = 0; g < 4; ++g) {
          acc[g][0] = mfma16(__builtin_bit_cast(bf16x8, v0),
                             __builtin_bit_cast(bf16x8, wreg[g][NCXW + cc]), acc[g][0]);
          acc[g][1] = mfma16(__builtin_bit_cast(bf16x8, v1),
                             __builtin_bit_cast(bf16x8, wreg[g][NCXW + cc]), acc[g][1]);
        }
      }

      // ---- dump partials: lane-consecutive f32x4 -> conflict-free ds_write_b128
#pragma unroll
      for (int g = 0; g < 4; ++g)
#pragma unroll
        for (int m = 0; m < MT; ++m)
          red[(g * 4 + ks) * (MT * 64) + m * 64 + lane] = acc[g][m];
      __syncthreads();

      // ---- reduce + cell update: threads 0..127 own (batch-quad, col)
      if (tid < 128) {
        f32x4 gate[4];
#pragma unroll
        for (int g = 0; g < 4; ++g) {
          f32x4 sum = red[(g * 4 + 0) * (MT * 64) + tid];
#pragma unroll
          for (int w = 1; w < 4; ++w) sum += red[(g * 4 + w) * (MT * 64) + tid];
          gate[g] = sum + (f32x4){bval[g], bval[g], bval[g], bval[g]};
        }
        const unsigned rstw = rbits[t] >> b0l;
        u16 hb[4];
#pragma unroll
        for (int r = 0; r < 4; ++r) {
          float cp = ((rstw >> r) & 1u) ? 0.f : creg[r];
          float i_ = sigm(gate[0][r]);
          float f_ = sigm(gate[1][r]);
          float g_ = tanhf(gate[2][r]);
          float o_ = sigm(gate[3][r]);
          float cn = fmaf(f_, cp, i_ * g_);
          float hn = o_ * tanhf(cn);
          creg[r] = cn;
          hv[r] = hn;
          hb[r] = f2bf(hn);
        }
        u16* hdst = (L == 0)
            ? xs1 + (size_t)((s + 1) & s1mask) * BH
            : h1b + (size_t)((t + 1) & h1mask) * BH;
        // publish h: agent-scope WRITE-THROUGH u32 stores (at LLC once vmcnt==0).
        // Pack column pairs via lane^1 shuffle; even lanes rows 0-1, odd rows 2-3.
#pragma unroll
        for (int r = 0; r < 4; ++r) {
          unsigned own = hb[r];
          unsigned oth = (unsigned)__shfl_xor((int)own, 1);
          unsigned pk = (tid & 1) ? ((oth & 0xffffu) | (own << 16))
                                  : (own | (oth << 16));
          if ((r >> 1) == (tid & 1))
            __hip_atomic_store(
                reinterpret_cast<unsigned*>(
                    hdst + (size_t)(half * BS + b0l + r) * H + (cl & ~1)),
                pk, __ATOMIC_RELAXED, __HIP_MEMORY_SCOPE_AGENT);
        }
        if (t == T - 1) {   // final states; L1 also emits its last out row here
#pragma unroll
          for (int r = 0; r < 4; ++r) {
            const size_t brow = (size_t)(half * BS + b0l + r);
            __builtin_nontemporal_store(
                hv[r], &out[OUT_HN + brow * 2 * H + (size_t)L * H + cl]);
            __builtin_nontemporal_store(
                creg[r], &out[OUT_CN + brow * 2 * H + (size_t)L * H + cl]);
            if (L == 1)
              __builtin_nontemporal_store(
                  hv[r], &out[(size_t)t * BH + brow * H + cl]);
          }
        }
      }
    }

    // ---- tail: drain publish stores, post flag; then OFF the critical path:
    // deferred out stores + next-step x prefetch (overlaps flag propagation).
    if (s < T) {
      __syncthreads();   // vmcnt(0) per wave: h stores are at LLC
      if (tid == 0)
        __hip_atomic_store(&flags[blockIdx.x], s + 1,
                           __ATOMIC_RELAXED, __HIP_MEMORY_SCOPE_AGENT);
      if (L == 1 && active && t < T - 1 && tid < 128) {
#pragma unroll
        for (int r = 0; r < 4; ++r)
          __builtin_nontemporal_store(
              hv[r], &out[(size_t)t * BH + (size_t)(half * BS + b0l + r) * H + cl]);
      }
      if (full) {
        if (L == 0) {
          if (s + 1 < T) load_xfrags(xin + (size_t)(s + 1) * B * D);
        } else {
          // L1's x for step s+1 = xs1[s+1], needs L0(half) flag >= s+1
          while (ldflag(flags, half * 64 + lane) < s + 1) __builtin_amdgcn_s_sleep(1);
          asm volatile("" ::: "memory");
          load_xfrags(xs1 + (size_t)((s + 1) & s1mask) * BH);
        }
      }
    }
  }
}

__global__ void __launch_bounds__(NTHR, 1) lstm_seq(
    const u16* __restrict__ xin,
    const u16* __restrict__ wx0, const u16* __restrict__ wh0,
    const u16* __restrict__ wx1, const u16* __restrict__ wh1,
    const float* __restrict__ bias0, const float* __restrict__ bias1,
    u16* __restrict__ xs1, u16* __restrict__ h1b,
    const float* __restrict__ c0, const int* __restrict__ reset,
    float* __restrict__ out, int* __restrict__ flags,
    int s1mask, int h1mask, int full) {
  __shared__ f32x4 red[4 * 4 * MT * 64];  // 32 KB partials
  __shared__ unsigned rbits[T];           // 1 KB packed reset bits (this half)
  __shared__ float lbias[64];             // this block's 64 bias rows
  // blockIdx = L*128 + half*64 + colblk
  const int group = blockIdx.x >> 7;
  const int half  = (blockIdx.x >> 6) & 1;
  const int col0  = (blockIdx.x & 63) << 4;
  if (group == 0)
    run_layer<0>(xin, wx0, wh0, bias0, xs1, h1b, c0, reset, out, flags, half, col0,
                 red, rbits, lbias, s1mask, h1mask, full);
  else
    run_layer<1>(nullptr, wx1, wh1, bias1, xs1, h1b, c0, reset, out, flags, half, col0,
                 red, rbits, lbias, s1mask, h1mask, full);
}

extern "C" void kernel_launch(void* const* d_in, const int* in_sizes, int n_in,
                              void* d_out, int out_size, void* d_ws, size_t ws_size,
                              hipStream_t stream) {
  (void)in_sizes; (void)n_in; (void)out_size;
  const float* input = (const float*)d_in[0];
  const int*   reset = (const int*)d_in[1];
  const float* h0    = (const float*)d_in[2];
  const float* c0    = (const float*)d_in[3];
  const float* Wih0  = (const float*)d_in[4];
  const float* Whh0  = (const float*)d_in[5];
  const float* bih0  = (const float*)d_in[6];
  const float* bhh0  = (const float*)d_in[7];
  const float* Wih1  = (const float*)d_in[8];
  const float* Whh1  = (const float*)d_in[9];
  const float* bih1  = (const float*)d_in[10];
  const float* bhh1  = (const float*)d_in[11];
  float* out = (float*)d_out;
  char* ws = (char*)d_ws;

  const size_t SLOT = (size_t)B * H * 2;             // one [B][H] bf16 slab (128 KB)
  const size_t FIXED = (size_t)G4 * D * 2 + 3 * (size_t)G4 * H * 2   // weights
                     + (size_t)T * B * D * 2                          // xin
                     + 2 * (size_t)G4 * 4 + 4096;                     // biases + flags + pad
  const bool full = ws_size >= FIXED + 2 * (size_t)(T + 1) * SLOT + 65536;
  const int d0 = full ? (T + 1) : 4;   // xs1 slots
  const int d1 = full ? (T + 1) : 2;   // h1b slots
  const int s1mask = full ? 511 : 3;   // slot index <= 256 < 512: identity in full mode
  const int h1mask = full ? 511 : 1;

  size_t off = 0;
  auto alloc = [&](size_t bytes) { size_t o = off; off += (bytes + 255) & ~(size_t)255; return o; };
  u16* wx0 = (u16*)(ws + alloc((size_t)G4 * D * 2));
  u16* wh0 = (u16*)(ws + alloc((size_t)G4 * H * 2));
  u16* wx1 = (u16*)(ws + alloc((size_t)G4 * H * 2));
  u16* wh1 = (u16*)(ws + alloc((size_t)G4 * H * 2));
  u16* xin = (u16*)(ws + alloc((size_t)T * B * D * 2));
  u16* xs1 = (u16*)(ws + alloc((size_t)d0 * SLOT));
  u16* h1b = (u16*)(ws + alloc((size_t)d1 * SLOT));
  float* pb0 = (float*)(ws + alloc((size_t)G4 * 4));
  float* pb1 = (float*)(ws + alloc((size_t)G4 * 4));
  int* flg = (int*)(ws + alloc(1024));

  cvt_bf16<<<1024, 256, 0, stream>>>(Wih0, wx0, G4 * D / 4);
  cvt_bf16<<<1024, 256, 0, stream>>>(Whh0, wh0, G4 * H / 4);
  cvt_bf16<<<1024, 256, 0, stream>>>(Wih1, wx1, G4 * H / 4);
  cvt_bf16<<<1024, 256, 0, stream>>>(Whh1, wh1, G4 * H / 4);
  cvt_bf16<<<2048, 256, 0, stream>>>(input, xin, T * B * D / 4);
  init_state<<<512, 256, 0, stream>>>(h0, xs1, h1b, bih0, bhh0, bih1, bhh1, pb0, pb1, flg);
  lstm_seq<<<NBLK, NTHR, 0, stream>>>(xin, wx0, wh0, wx1, wh1, pb0, pb1,
                                      xs1, h1b, c0, reset, out, flg,
                                      s1mask, h1mask, full ? 1 : 0);
}